// Round 4
// baseline (591.693 us; speedup 1.0000x reference)
//
#include <hip/hip_runtime.h>

typedef unsigned short u16;
typedef short bf8 __attribute__((ext_vector_type(8)));   // 8 bf16 = 4 VGPR (MFMA A/B frag)
typedef float f32x4 __attribute__((ext_vector_type(4))); // MFMA C/D frag

#define Bc 8
#define Hc 8
#define Lc 1024
#define Dc 512
#define HDc 64

// ---------- bf16 helpers ----------
__device__ __forceinline__ u16 f2bf(float f) {
    unsigned int x; __builtin_memcpy(&x, &f, 4);
    x = x + 0x7fffu + ((x >> 16) & 1u);  // RNE
    return (u16)(x >> 16);
}
union S8 { bf8 v; u16 s[8]; };

// ---------- rel fp32 -> bf16 ----------
__global__ __launch_bounds__(256) void relcvt(const float* __restrict__ src,
                                              u16* __restrict__ dst) {
    const int idx = blockIdx.x * 256 + threadIdx.x;           // 16384 float4
    const float4 v = *(const float4*)(src + (size_t)idx * 4);
    ushort4 o; o.x = f2bf(v.x); o.y = f2bf(v.y); o.z = f2bf(v.z); o.w = f2bf(v.w);
    *(ushort4*)(dst + (size_t)idx * 4) = o;
}

// ---------- W (KxN fp32) -> WT (NxK bf16), 4 weights ----------
__global__ __launch_bounds__(256) void wtrans(
    const float* __restrict__ w0, const float* __restrict__ w1,
    const float* __restrict__ w2, const float* __restrict__ w3,
    u16* __restrict__ o0, u16* __restrict__ o1,
    u16* __restrict__ o2, u16* __restrict__ o3)
{
    const float* W; u16* O;
    switch (blockIdx.z) {
        case 0: W = w0; O = o0; break;
        case 1: W = w1; O = o1; break;
        case 2: W = w2; O = o2; break;
        default: W = w3; O = o3; break;
    }
    __shared__ float tile[64][65];
    const int t = threadIdx.x;
    const int k0 = blockIdx.x * 64, n0 = blockIdx.y * 64;
#pragma unroll
    for (int s = 0; s < 4; ++s) {
        const int idx = s * 256 + t;
        const int r = idx >> 4, c = (idx & 15) * 4;
        const float4 v = *(const float4*)(W + (size_t)(k0 + r) * Dc + n0 + c);
        tile[r][c] = v.x; tile[r][c + 1] = v.y; tile[r][c + 2] = v.z; tile[r][c + 3] = v.w;
    }
    __syncthreads();
#pragma unroll
    for (int s = 0; s < 2; ++s) {
        const int idx = s * 256 + t;
        const int rn = idx >> 3, ck = (idx & 7) * 8;
        S8 o;
#pragma unroll
        for (int u = 0; u < 8; ++u) o.s[u] = f2bf(tile[ck + u][rn]);
        *(bf8*)(O + (size_t)(n0 + rn) * Dc + k0 + ck) = o.v;
    }
}

// ---------- MFMA GEMM: Y = A(8192x512) @ WT^T + bias ----------
// 128x64 tile, grid 512 (2 blocks/CU exact). XCD swizzle: mt = xcd*8 + chunk so each
// XCD owns a contiguous 2MB A-panel (read once) + WT 0.5MB, both L2-resident.
// Double-buffered LDS, register prefetch, 1 barrier/iter, 16 MFMA/iter.
// A: fp32 (aF32=1) or bf16; WT: bf16 [N][K]; mode 0: f32 flat (nt store); 1: bf16 head-split
__global__ __launch_bounds__(256) void gemm_mfma(
    const void* __restrict__ A, const u16* __restrict__ WT,
    const float* __restrict__ bias, void* __restrict__ Y,
    int aF32, int mode)
{
    __shared__ u16 As[2][128][72];
    __shared__ u16 Bs[2][64][72];

    const int wgid = blockIdx.x;
    const int xcd = wgid & 7, rr = wgid >> 3;
    const int mt = xcd * 8 + (rr >> 3), ntl = rr & 7;
    const int m0 = mt * 128, n0 = ntl * 64;

    const int t = threadIdx.x;
    const int w = t >> 6, lane = t & 63, quad = lane >> 4, l15 = lane & 15;

    f32x4 acc[2][4] = {};

    // prologue: stage k0 = 0 into buf 0
    {
#pragma unroll
        for (int s = 0; s < 4; ++s) {
            const int idx = s * 256 + t, r = idx >> 3, cb = (idx & 7) * 8;
            S8 o;
            if (aF32) {
                const float* ap = (const float*)A + (size_t)(m0 + r) * Dc + cb;
                const float4 v0 = *(const float4*)ap, v1 = *(const float4*)(ap + 4);
                o.s[0] = f2bf(v0.x); o.s[1] = f2bf(v0.y); o.s[2] = f2bf(v0.z); o.s[3] = f2bf(v0.w);
                o.s[4] = f2bf(v1.x); o.s[5] = f2bf(v1.y); o.s[6] = f2bf(v1.z); o.s[7] = f2bf(v1.w);
            } else {
                o.v = *(const bf8*)((const u16*)A + (size_t)(m0 + r) * Dc + cb);
            }
            *(bf8*)&As[0][r][cb] = o.v;
        }
#pragma unroll
        for (int s = 0; s < 2; ++s) {
            const int idx = s * 256 + t, r = idx >> 3, cb = (idx & 7) * 8;
            *(bf8*)&Bs[0][r][cb] = *(const bf8*)(WT + (size_t)(n0 + r) * Dc + cb);
        }
    }

    int cur = 0;
    for (int k0 = 0; k0 < Dc; k0 += 64) {
        __syncthreads();                 // buf[cur] ready; buf[cur^1] reads drained
        const bool pf = (k0 + 64 < Dc);
        float4 fv[4][2]; bf8 av[4] = {}; bf8 bv[2] = {};
        if (pf) {                        // issue next-tile loads early
            const int kn = k0 + 64;
#pragma unroll
            for (int s = 0; s < 4; ++s) {
                const int idx = s * 256 + t, r = idx >> 3, cb = (idx & 7) * 8;
                if (aF32) {
                    const float* ap = (const float*)A + (size_t)(m0 + r) * Dc + kn + cb;
                    fv[s][0] = *(const float4*)ap; fv[s][1] = *(const float4*)(ap + 4);
                } else {
                    av[s] = *(const bf8*)((const u16*)A + (size_t)(m0 + r) * Dc + kn + cb);
                }
            }
#pragma unroll
            for (int s = 0; s < 2; ++s) {
                const int idx = s * 256 + t, r = idx >> 3, cb = (idx & 7) * 8;
                bv[s] = *(const bf8*)(WT + (size_t)(n0 + r) * Dc + kn + cb);
            }
        }

#pragma unroll
        for (int ks = 0; ks < 2; ++ks) {
            const bf8 a0 = *(const bf8*)&As[cur][w * 32 + l15][ks * 32 + quad * 8];
            const bf8 a1 = *(const bf8*)&As[cur][w * 32 + 16 + l15][ks * 32 + quad * 8];
#pragma unroll
            for (int nt = 0; nt < 4; ++nt) {
                const bf8 b = *(const bf8*)&Bs[cur][nt * 16 + l15][ks * 32 + quad * 8];
                acc[0][nt] = __builtin_amdgcn_mfma_f32_16x16x32_bf16(a0, b, acc[0][nt], 0, 0, 0);
                acc[1][nt] = __builtin_amdgcn_mfma_f32_16x16x32_bf16(a1, b, acc[1][nt], 0, 0, 0);
            }
        }

        if (pf) {                        // convert + ds_write into other buffer
#pragma unroll
            for (int s = 0; s < 4; ++s) {
                const int idx = s * 256 + t, r = idx >> 3, cb = (idx & 7) * 8;
                S8 o;
                if (aF32) {
                    o.s[0] = f2bf(fv[s][0].x); o.s[1] = f2bf(fv[s][0].y);
                    o.s[2] = f2bf(fv[s][0].z); o.s[3] = f2bf(fv[s][0].w);
                    o.s[4] = f2bf(fv[s][1].x); o.s[5] = f2bf(fv[s][1].y);
                    o.s[6] = f2bf(fv[s][1].z); o.s[7] = f2bf(fv[s][1].w);
                } else { o.v = av[s]; }
                *(bf8*)&As[cur ^ 1][r][cb] = o.v;
            }
#pragma unroll
            for (int s = 0; s < 2; ++s) {
                const int idx = s * 256 + t, r = idx >> 3, cb = (idx & 7) * 8;
                *(bf8*)&Bs[cur ^ 1][r][cb] = bv[s];
            }
            cur ^= 1;
        }
    }

#pragma unroll
    for (int nt = 0; nt < 4; ++nt) {
        const int n = n0 + nt * 16 + l15;
        const float bv2 = bias[n];
#pragma unroll
        for (int mi = 0; mi < 2; ++mi) {
#pragma unroll
            for (int reg = 0; reg < 4; ++reg) {
                const int m = m0 + w * 32 + mi * 16 + quad * 4 + reg;
                const float val = acc[mi][nt][reg] + bv2;
                if (mode == 0) {
                    __builtin_nontemporal_store(val, (float*)Y + (size_t)m * Dc + n);
                } else {
                    const int b = m >> 10, l = m & 1023;
                    const int h = n >> 6, hd = n & 63;
                    ((u16*)Y)[(((size_t)(b * Hc + h)) * Lc + l) * HDc + hd] = f2bf(val);
                }
            }
        }
    }
}

// ---------- MFMA attention ----------
// grid (64 = bh, 8 = px): same-head blocks colocate on one XCD (q/k/v/rel L2-resident).
// Block handles i-tiles it = px and 15-px: perfectly balanced (17 j-tiles per pass).
// K/V double-buffered in LDS, register prefetch.
// score(i,j) = (q_i.k_j + q_i.E[1023-i+j]) / 8 ; two-pass softmax (logits O(1), no max).
// rel b-frags read direct from global (L2-resident; OOB rows clamped -> masked anyway).
// rel skew applied via IN-WAVE SHUFFLE (producer of rs[Rl][cp] is same quad/reg):
//   needed value = aR[nt+carry][reg] from lane quad*16 + ((l15+15-r4)&15), carry = l15>r4.
// P kept twice: bf16 p16 (PV MFMA A-frags, wave-private rows) + f32 p32 (coalesced store).
__global__ __launch_bounds__(256) void attn_mfma(
    const u16* __restrict__ q, const u16* __restrict__ k,
    const u16* __restrict__ v, const u16* __restrict__ rel,
    float* __restrict__ attn, u16* __restrict__ ows)
{
    __shared__ u16 kps[2][64][72];   // K tile [j][d], double-buffered
    __shared__ u16 vst[2][64][72];   // V^T tile [d][j], col-blocks rotated, double-buffered
    __shared__ u16 p16[64][72];      // bf16 P (PV A-frags; rows wave-private)
    __shared__ float p32[64][68];    // f32 P (coalesced nontemporal attn store)
    __shared__ float ls[64];         // row sum of exp; then 1/sum

    const int bh = blockIdx.x;
    const int px = blockIdx.y;                  // 0..7
    const int t = threadIdx.x;
    const int w = t >> 6, lane = t & 63, quad = lane >> 4, l15 = lane & 15;
    const int nt0 = 3 - w;                      // per-wave rel nt-window start
    const size_t qb = ((size_t)bh << 10);
    const int sr = t >> 3, scb = (t & 7) * 8;   // staging coords: rows sr / sr+32, col blk scb

    // rel-skew shuffle constants (invariant): for row r4 = quad*4+reg,
    // src lane = quad*16 + ((l15+15-r4)&15); carry selects aR[nt+1] vs aR[nt].
    int sl[4]; bool cy[4];
#pragma unroll
    for (int reg = 0; reg < 4; ++reg) {
        const int s = l15 + 15 - (quad * 4 + reg);
        sl[reg] = (quad << 4) | (s & 15);
        cy[reg] = s >= 16;
    }

    for (int seg = 0; seg < 2; ++seg) {
        const int it = seg ? (15 - px) : px;
        const int i0 = it * 64;

        __syncthreads();                        // prior segment's LDS reads done
        if (t < 64) ls[t] = 0.f;

        // q fragments live in registers for this i-tile
        bf8 aq[2];
#pragma unroll
        for (int ks = 0; ks < 2; ++ks)
            aq[ks] = *(const bf8*)(q + (qb + i0 + w * 16 + l15) * HDc + ks * 32 + quad * 8);

        // ================= pass A: row sums =================
        {   // prologue: stage jt=0 K
            const bf8 k0r = *(const bf8*)(k + (qb + sr) * HDc + scb);
            const bf8 k1r = *(const bf8*)(k + (qb + 32 + sr) * HDc + scb);
            *(bf8*)&kps[0][sr][scb] = k0r;
            *(bf8*)&kps[0][32 + sr][scb] = k1r;
        }
        int cur = 0;
        for (int jt = 0; jt <= it; ++jt) {
            const int j0 = jt * 64;
            const int mb = 960 - i0 + j0 + nt0 * 16;
            __syncthreads();                    // buf[cur] writes visible; prev reads drained
            const bool pf = (jt < it);
            bf8 kn0 = {}, kn1 = {};
            if (pf) {
                kn0 = *(const bf8*)(k + (qb + j0 + 64 + sr) * HDc + scb);
                kn1 = *(const bf8*)(k + (qb + j0 + 96 + sr) * HDc + scb);
            }

            f32x4 aS[4] = {}; f32x4 aR[5] = {};
#pragma unroll
            for (int ks = 0; ks < 2; ++ks) {
                const bf8 a = aq[ks];
#pragma unroll
                for (int nt = 0; nt < 4; ++nt) {
                    const bf8 b = *(const bf8*)&kps[cur][nt * 16 + l15][ks * 32 + quad * 8];
                    aS[nt] = __builtin_amdgcn_mfma_f32_16x16x32_bf16(a, b, aS[nt], 0, 0, 0);
                }
#pragma unroll
                for (int nt = 0; nt < 5; ++nt) {
                    int row = mb + nt * 16 + l15;
                    row = row > 1023 ? 1023 : row;   // OOB rows feed only masked elements
                    const bf8 b = *(const bf8*)(rel + (size_t)row * HDc + ks * 32 + quad * 8);
                    aR[nt] = __builtin_amdgcn_mfma_f32_16x16x32_bf16(a, b, aR[nt], 0, 0, 0);
                }
            }

            // rel skew via in-wave shuffle (register-only)
            float g[5][4];
#pragma unroll
            for (int m = 0; m < 5; ++m)
#pragma unroll
                for (int reg = 0; reg < 4; ++reg)
                    g[m][reg] = __shfl(aR[m][reg], sl[reg], 64);

            float psum[4] = {0.f, 0.f, 0.f, 0.f};
#pragma unroll
            for (int nt = 0; nt < 4; ++nt) {
#pragma unroll
                for (int reg = 0; reg < 4; ++reg) {
                    const int Rl = w * 16 + quad * 4 + reg;
                    const float relv = cy[reg] ? g[nt + 1][reg] : g[nt][reg];
                    const float sc = (aS[nt][reg] + relv) * 0.125f;
                    const bool valid = (j0 + nt * 16 + l15) <= (i0 + Rl);
                    psum[reg] += valid ? __expf(sc) : 0.f;
                }
            }
#pragma unroll
            for (int m = 1; m < 16; m <<= 1)
#pragma unroll
                for (int reg = 0; reg < 4; ++reg) psum[reg] += __shfl_xor(psum[reg], m, 64);
            if (l15 == 0) {
#pragma unroll
                for (int reg = 0; reg < 4; ++reg) ls[w * 16 + quad * 4 + reg] += psum[reg];
            }
            if (pf) {
                *(bf8*)&kps[cur ^ 1][sr][scb] = kn0;
                *(bf8*)&kps[cur ^ 1][32 + sr][scb] = kn1;
                cur ^= 1;
            }
        }

        __syncthreads();                        // pass-A reads/accums done
        if (t < 64) ls[t] = 1.f / ls[t];

        f32x4 acc[4] = {};                      // PV accumulator (MFMA C layout)

        // ================= pass B: attn write + PV =================
        {   // prologue: stage jt=0 K + V
            const bf8 k0r = *(const bf8*)(k + (qb + sr) * HDc + scb);
            const bf8 k1r = *(const bf8*)(k + (qb + 32 + sr) * HDc + scb);
            S8 v0; v0.v = *(const bf8*)(v + (qb + sr) * HDc + scb);
            S8 v1; v1.v = *(const bf8*)(v + (qb + 32 + sr) * HDc + scb);
            *(bf8*)&kps[0][sr][scb] = k0r;
            *(bf8*)&kps[0][32 + sr][scb] = k1r;
            const int cp0 = (sr & 7) + 8 * (((sr >> 3) + (scb >> 3)) & 7);
            const int cp1 = (sr & 7) + 8 * ((4 + (sr >> 3) + (scb >> 3)) & 7);
#pragma unroll
            for (int u = 0; u < 8; ++u) vst[0][scb + u][cp0] = v0.s[u];
#pragma unroll
            for (int u = 0; u < 8; ++u) vst[0][scb + u][cp1] = v1.s[u];
        }
        cur = 0;
        for (int jt = 0; jt <= it; ++jt) {
            const int j0 = jt * 64;
            const int mb = 960 - i0 + j0 + nt0 * 16;
            __syncthreads();                    // buf[cur] ready; ls inversion visible (jt=0)
            const bool pf = (jt < it);
            bf8 kn0 = {}, kn1 = {}, vn0 = {}, vn1 = {};
            if (pf) {
                kn0 = *(const bf8*)(k + (qb + j0 + 64 + sr) * HDc + scb);
                kn1 = *(const bf8*)(k + (qb + j0 + 96 + sr) * HDc + scb);
                vn0 = *(const bf8*)(v + (qb + j0 + 64 + sr) * HDc + scb);
                vn1 = *(const bf8*)(v + (qb + j0 + 96 + sr) * HDc + scb);
            }

            f32x4 aS[4] = {}; f32x4 aR[5] = {};
#pragma unroll
            for (int ks = 0; ks < 2; ++ks) {
                const bf8 a = aq[ks];
#pragma unroll
                for (int nt = 0; nt < 4; ++nt) {
                    const bf8 b = *(const bf8*)&kps[cur][nt * 16 + l15][ks * 32 + quad * 8];
                    aS[nt] = __builtin_amdgcn_mfma_f32_16x16x32_bf16(a, b, aS[nt], 0, 0, 0);
                }
#pragma unroll
                for (int nt = 0; nt < 5; ++nt) {
                    int row = mb + nt * 16 + l15;
                    row = row > 1023 ? 1023 : row;
                    const bf8 b = *(const bf8*)(rel + (size_t)row * HDc + ks * 32 + quad * 8);
                    aR[nt] = __builtin_amdgcn_mfma_f32_16x16x32_bf16(a, b, aR[nt], 0, 0, 0);
                }
            }

            float g[5][4];
#pragma unroll
            for (int m = 0; m < 5; ++m)
#pragma unroll
                for (int reg = 0; reg < 4; ++reg)
                    g[m][reg] = __shfl(aR[m][reg], sl[reg], 64);

            float ils[4];
#pragma unroll
            for (int reg = 0; reg < 4; ++reg) ils[reg] = ls[w * 16 + quad * 4 + reg];

#pragma unroll
            for (int nt = 0; nt < 4; ++nt) {
#pragma unroll
                for (int reg = 0; reg < 4; ++reg) {
                    const int Rl = w * 16 + quad * 4 + reg;
                    const float relv = cy[reg] ? g[nt + 1][reg] : g[nt][reg];
                    const float sc = (aS[nt][reg] + relv) * 0.125f;
                    const bool valid = (j0 + nt * 16 + l15) <= (i0 + Rl);
                    const float p = valid ? __expf(sc) * ils[reg] : 0.f;
                    p16[Rl][nt * 16 + l15] = f2bf(p);
                    p32[Rl][nt * 16 + l15] = p;
                }
            }
            asm volatile("" ::: "memory");      // P writes ordered before pa reads

            // PV via MFMA: acc[nt] += P(16x64) x V(64x16); p16 rows wave-private (in-order DS).
#pragma unroll
            for (int ks = 0; ks < 2; ++ks) {
                const bf8 pa = *(const bf8*)((const u16*)&p16[w * 16 + l15][0] + ks * 32 + quad * 8);
#pragma unroll
                for (int nt = 0; nt < 4; ++nt) {
                    const int d = nt * 16 + l15;
                    const bf8 vb = *(const bf8*)&vst[cur][d][8 * (((ks * 4 + quad) + (d >> 3)) & 7)];
                    acc[nt] = __builtin_amdgcn_mfma_f32_16x16x32_bf16(pa, vb, acc[nt], 0, 0, 0);
                }
            }

            if (pf) {                           // stage next tile into other buffer
                *(bf8*)&kps[cur ^ 1][sr][scb] = kn0;
                *(bf8*)&kps[cur ^ 1][32 + sr][scb] = kn1;
                S8 a0; a0.v = vn0; S8 a1; a1.v = vn1;
                const int cp0 = (sr & 7) + 8 * (((sr >> 3) + (scb >> 3)) & 7);
                const int cp1 = (sr & 7) + 8 * ((4 + (sr >> 3) + (scb >> 3)) & 7);
#pragma unroll
                for (int u = 0; u < 8; ++u) vst[cur ^ 1][scb + u][cp0] = a0.s[u];
#pragma unroll
                for (int u = 0; u < 8; ++u) vst[cur ^ 1][scb + u][cp1] = a1.s[u];
                cur ^= 1;
            }

            __syncthreads();                    // B2: all waves' f32 P visible
            // coalesced attn store: lanes 0-15 emit 256B/row, nontemporal (protect L2)
            const int trow = t >> 4, tcol = (t & 15) * 4;
#pragma unroll
            for (int s = 0; s < 4; ++s) {
                const f32x4 p4 = *(const f32x4*)&p32[trow + 16 * s][tcol];
                __builtin_nontemporal_store(p4,
                    (f32x4*)(attn + ((size_t)bh * Lc + i0 + trow + 16 * s) * Lc + j0 + tcol));
            }
            // next TOP barrier protects p16/p32 from next-tile overwrites
        }

        // epilogue: out (already normalized), MFMA C layout
        const int bb = bh >> 3, hh = bh & 7;
#pragma unroll
        for (int nt = 0; nt < 4; ++nt)
#pragma unroll
            for (int reg = 0; reg < 4; ++reg)
                ows[((size_t)(bb * Lc + i0 + w * 16 + quad * 4 + reg)) * Dc + hh * HDc + nt * 16 + l15]
                    = f2bf(acc[nt][reg]);

        // zero-fill attn cols beyond the causal tiles (nontemporal)
        const int jend = (it + 1) * 64;
        if (jend + t * 4 < Lc) {
            const f32x4 z = {0.f, 0.f, 0.f, 0.f};
            for (int r = 0; r < 64; ++r)
                __builtin_nontemporal_store(z,
                    (f32x4*)(attn + ((size_t)bh * Lc + i0 + r) * Lc + jend + t * 4));
        }
    }
}

// ---------- launch ----------
extern "C" void kernel_launch(void* const* d_in, const int* in_sizes, int n_in,
                              void* d_out, int out_size, void* d_ws, size_t ws_size,
                              hipStream_t stream)
{
    const float* x_q = (const float*)d_in[0];
    const float* x_k = (const float*)d_in[1];
    const float* x_v = (const float*)d_in[2];
    // d_in[3] = mask — causal, folded analytically
    const float* Wq = (const float*)d_in[4];
    const float* bq = (const float*)d_in[5];
    const float* Wk = (const float*)d_in[6];
    const float* bk = (const float*)d_in[7];
    const float* Wv = (const float*)d_in[8];
    const float* bv = (const float*)d_in[9];
    const float* Wo = (const float*)d_in[10];
    const float* bo = (const float*)d_in[11];
    const float* rel = (const float*)d_in[12];

    float* out  = (float*)d_out;
    float* attn = out + (size_t)Bc * Lc * Dc;

    // ws carve (bf16)
    u16* relbf = (u16*)d_ws;                             // 1024*64
    u16* wqT = relbf + (size_t)1024 * 64;                // 512*512 each
    u16* wkT = wqT + (size_t)Dc * Dc;
    u16* wvT = wkT + (size_t)Dc * Dc;
    u16* woT = wvT + (size_t)Dc * Dc;
    u16* qbf = woT + (size_t)Dc * Dc;                    // head-split (B,H,L,HD)
    u16* kbf = qbf + (size_t)Bc * Lc * Dc;
    u16* vbf = kbf + (size_t)Bc * Lc * Dc;
    u16* owsbf = vbf + (size_t)Bc * Lc * Dc;             // (B,L,D) flat

    relcvt<<<64, 256, 0, stream>>>(rel, relbf);
    wtrans<<<dim3(8, 8, 4), 256, 0, stream>>>(Wq, Wk, Wv, Wo, wqT, wkT, wvT, woT);

    gemm_mfma<<<512, 256, 0, stream>>>(x_q, wqT, bq, qbf, 1, 1);
    gemm_mfma<<<512, 256, 0, stream>>>(x_k, wkT, bk, kbf, 1, 1);
    gemm_mfma<<<512, 256, 0, stream>>>(x_v, wvT, bv, vbf, 1, 1);

    attn_mfma<<<dim3(64, 8), 256, 0, stream>>>(qbf, kbf, vbf, relbf, attn, owsbf);

    gemm_mfma<<<512, 256, 0, stream>>>(owsbf, woT, bo, out, 0, 0);
}

// Round 5
// 451.522 us; speedup vs baseline: 1.3104x; 1.3104x over previous
//
#include <hip/hip_runtime.h>

typedef unsigned short u16;
typedef short bf8 __attribute__((ext_vector_type(8)));   // 8 bf16 = 4 VGPR (MFMA A/B frag)
typedef float f32x4 __attribute__((ext_vector_type(4))); // MFMA C/D frag

#define Bc 8
#define Hc 8
#define Lc 1024
#define Dc 512
#define HDc 64

// ---------- bf16 helpers ----------
__device__ __forceinline__ u16 f2bf(float f) {
    unsigned int x; __builtin_memcpy(&x, &f, 4);
    x = x + 0x7fffu + ((x >> 16) & 1u);  // RNE
    return (u16)(x >> 16);
}
union S8 { bf8 v; u16 s[8]; };

// ---------- rel fp32 -> bf16 ----------
__global__ __launch_bounds__(256) void relcvt(const float* __restrict__ src,
                                              u16* __restrict__ dst) {
    const int idx = blockIdx.x * 256 + threadIdx.x;           // 16384 float4
    const float4 v = *(const float4*)(src + (size_t)idx * 4);
    ushort4 o; o.x = f2bf(v.x); o.y = f2bf(v.y); o.z = f2bf(v.z); o.w = f2bf(v.w);
    *(ushort4*)(dst + (size_t)idx * 4) = o;
}

// ---------- W (KxN fp32) -> WT (NxK bf16), 4 weights ----------
__global__ __launch_bounds__(256) void wtrans(
    const float* __restrict__ w0, const float* __restrict__ w1,
    const float* __restrict__ w2, const float* __restrict__ w3,
    u16* __restrict__ o0, u16* __restrict__ o1,
    u16* __restrict__ o2, u16* __restrict__ o3)
{
    const float* W; u16* O;
    switch (blockIdx.z) {
        case 0: W = w0; O = o0; break;
        case 1: W = w1; O = o1; break;
        case 2: W = w2; O = o2; break;
        default: W = w3; O = o3; break;
    }
    __shared__ float tile[64][65];
    const int t = threadIdx.x;
    const int k0 = blockIdx.x * 64, n0 = blockIdx.y * 64;
#pragma unroll
    for (int s = 0; s < 4; ++s) {
        const int idx = s * 256 + t;
        const int r = idx >> 4, c = (idx & 15) * 4;
        const float4 v = *(const float4*)(W + (size_t)(k0 + r) * Dc + n0 + c);
        tile[r][c] = v.x; tile[r][c + 1] = v.y; tile[r][c + 2] = v.z; tile[r][c + 3] = v.w;
    }
    __syncthreads();
#pragma unroll
    for (int s = 0; s < 2; ++s) {
        const int idx = s * 256 + t;
        const int rn = idx >> 3, ck = (idx & 7) * 8;
        S8 o;
#pragma unroll
        for (int u = 0; u < 8; ++u) o.s[u] = f2bf(tile[ck + u][rn]);
        *(bf8*)(O + (size_t)(n0 + rn) * Dc + k0 + ck) = o.v;
    }
}

// ---------- MFMA GEMM: Y = A(8192x512) @ WT^T + bias ----------
// 64x64 tile, grid 1024 (4 blocks/CU). XCD swizzle: mt = xcd + 8*chunk so each XCD's
// consecutive blocks are the 8 n-tiles of one m-panel -> A fetched once chip-wide,
// WT (512 KB) L2-resident. Double-buffered LDS, register prefetch, 1 barrier/iter.
// A: fp32 (aF32=1) or bf16; WT: bf16 [N][K]; mode 0: f32 flat (nt store); 1: bf16 head-split
__global__ __launch_bounds__(256) void gemm_mfma(
    const void* __restrict__ A, const u16* __restrict__ WT,
    const float* __restrict__ bias, void* __restrict__ Y,
    int aF32, int mode)
{
    __shared__ u16 As[2][64][72];
    __shared__ u16 Bs[2][64][72];

    const int wgid = blockIdx.x;
    const int xcd = wgid & 7, rr = wgid >> 3;
    const int mt = xcd + 8 * (rr >> 3), ntile = rr & 7;
    const int m0 = mt * 64, n0 = ntile * 64;

    const int t = threadIdx.x;
    const int w = t >> 6, lane = t & 63, quad = lane >> 4, l15 = lane & 15;
    const int ra = t >> 2, ca = (t & 3) * 16;   // staging: row, 16-col block

    f32x4 acc[4] = {};

    // prologue: stage k0 = 0 into buf 0
    {
        S8 o0, o1;
        if (aF32) {
            const float* ap = (const float*)A + (size_t)(m0 + ra) * Dc + ca;
            const float4 v0 = *(const float4*)ap,       v1 = *(const float4*)(ap + 4);
            const float4 v2 = *(const float4*)(ap + 8), v3 = *(const float4*)(ap + 12);
            o0.s[0] = f2bf(v0.x); o0.s[1] = f2bf(v0.y); o0.s[2] = f2bf(v0.z); o0.s[3] = f2bf(v0.w);
            o0.s[4] = f2bf(v1.x); o0.s[5] = f2bf(v1.y); o0.s[6] = f2bf(v1.z); o0.s[7] = f2bf(v1.w);
            o1.s[0] = f2bf(v2.x); o1.s[1] = f2bf(v2.y); o1.s[2] = f2bf(v2.z); o1.s[3] = f2bf(v2.w);
            o1.s[4] = f2bf(v3.x); o1.s[5] = f2bf(v3.y); o1.s[6] = f2bf(v3.z); o1.s[7] = f2bf(v3.w);
        } else {
            const u16* ap = (const u16*)A + (size_t)(m0 + ra) * Dc + ca;
            o0.v = *(const bf8*)ap; o1.v = *(const bf8*)(ap + 8);
        }
        *(bf8*)&As[0][ra][ca] = o0.v; *(bf8*)&As[0][ra][ca + 8] = o1.v;
        const u16* bp = WT + (size_t)(n0 + ra) * Dc + ca;
        *(bf8*)&Bs[0][ra][ca] = *(const bf8*)bp;
        *(bf8*)&Bs[0][ra][ca + 8] = *(const bf8*)(bp + 8);
    }

    int cur = 0;
    for (int k0 = 0; k0 < Dc; k0 += 64) {
        __syncthreads();                 // buf[cur] ready; buf[cur^1] reads drained
        const bool pf = (k0 + 64 < Dc);
        float4 v0, v1, v2, v3; bf8 an0 = {}, an1 = {}, bn0 = {}, bn1 = {};
        if (pf) {                        // issue next-tile loads early
            const int kn = k0 + 64;
            if (aF32) {
                const float* ap = (const float*)A + (size_t)(m0 + ra) * Dc + kn + ca;
                v0 = *(const float4*)ap;       v1 = *(const float4*)(ap + 4);
                v2 = *(const float4*)(ap + 8); v3 = *(const float4*)(ap + 12);
            } else {
                const u16* ap = (const u16*)A + (size_t)(m0 + ra) * Dc + kn + ca;
                an0 = *(const bf8*)ap; an1 = *(const bf8*)(ap + 8);
            }
            const u16* bp = WT + (size_t)(n0 + ra) * Dc + kn + ca;
            bn0 = *(const bf8*)bp; bn1 = *(const bf8*)(bp + 8);
        }

#pragma unroll
        for (int ks = 0; ks < 2; ++ks) {
            const bf8 a = *(const bf8*)&As[cur][w * 16 + l15][ks * 32 + quad * 8];
#pragma unroll
            for (int nt = 0; nt < 4; ++nt) {
                const bf8 b = *(const bf8*)&Bs[cur][nt * 16 + l15][ks * 32 + quad * 8];
                acc[nt] = __builtin_amdgcn_mfma_f32_16x16x32_bf16(a, b, acc[nt], 0, 0, 0);
            }
        }

        if (pf) {                        // convert + ds_write into other buffer
            S8 o0, o1;
            if (aF32) {
                o0.s[0] = f2bf(v0.x); o0.s[1] = f2bf(v0.y); o0.s[2] = f2bf(v0.z); o0.s[3] = f2bf(v0.w);
                o0.s[4] = f2bf(v1.x); o0.s[5] = f2bf(v1.y); o0.s[6] = f2bf(v1.z); o0.s[7] = f2bf(v1.w);
                o1.s[0] = f2bf(v2.x); o1.s[1] = f2bf(v2.y); o1.s[2] = f2bf(v2.z); o1.s[3] = f2bf(v2.w);
                o1.s[4] = f2bf(v3.x); o1.s[5] = f2bf(v3.y); o1.s[6] = f2bf(v3.z); o1.s[7] = f2bf(v3.w);
            } else { o0.v = an0; o1.v = an1; }
            *(bf8*)&As[cur ^ 1][ra][ca] = o0.v; *(bf8*)&As[cur ^ 1][ra][ca + 8] = o1.v;
            *(bf8*)&Bs[cur ^ 1][ra][ca] = bn0;  *(bf8*)&Bs[cur ^ 1][ra][ca + 8] = bn1;
            cur ^= 1;
        }
    }

#pragma unroll
    for (int nt = 0; nt < 4; ++nt) {
        const int n = n0 + nt * 16 + l15;
        const float bv = bias[n];
#pragma unroll
        for (int reg = 0; reg < 4; ++reg) {
            const int m = m0 + w * 16 + quad * 4 + reg;
            const float val = acc[nt][reg] + bv;
            if (mode == 0) {
                __builtin_nontemporal_store(val, (float*)Y + (size_t)m * Dc + n);
            } else {
                const int b = m >> 10, l = m & 1023;
                const int h = n >> 6, hd = n & 63;
                ((u16*)Y)[(((size_t)(b * Hc + h)) * Lc + l) * HDc + hd] = f2bf(val);
            }
        }
    }
}

// ---------- MFMA attention ----------
// grid (64 = bh, 8 = px): same-head blocks colocate on one XCD (q/k/v/rel L2-resident).
// Block handles i-tiles it = px and 15-px: perfectly balanced (17 j-tiles per pass).
// K double-buffered (register prefetch); V single-buffered (write after B2).
// rel staged in LDS as a ROLLING 3-HALF RING es[3][64][72]: window [mbase, mbase+127],
// advances 64 rows per j-tile; half for tile jt+1 staged during tile jt (coalesced,
// shared by all waves) -> replaces per-wave divergent global gathers (16 sectors/load).
// score(i,j) = (q_i.k_j + q_i.E[1023-i+j]) / 8 ; two-pass softmax (logits O(1), no max).
// rs rows are wave-private: rel scores (f32); then bf16 P (f32 cols 0..31) for PV MFMA
// and f32 P (cols 32..95) for the coalesced float4 nontemporal attn store.
__global__ __launch_bounds__(256) void attn_mfma(
    const u16* __restrict__ q, const u16* __restrict__ k,
    const u16* __restrict__ v, const u16* __restrict__ rel,
    float* __restrict__ attn, u16* __restrict__ ows)
{
    __shared__ u16 kps[2][64][72];   // K tile [j][d], double-buffered
    __shared__ u16 vst[64][72];      // V^T tile [d][j], col-blocks rotated, single-buffered
    __shared__ u16 es[3][64][72];    // rel ring: 3 halves of 64 rows
    __shared__ float rs[64][96];     // wave-private: rel scores / bf16 P / f32 P
    __shared__ float ls[64];         // row sum of exp; then 1/sum

    const int bh = blockIdx.x;
    const int px = blockIdx.y;                  // 0..7
    const int t = threadIdx.x;
    const int w = t >> 6, lane = t & 63, quad = lane >> 4, l15 = lane & 15;
    const size_t qb = ((size_t)bh << 10);
    const int sr = t >> 3, scb = (t & 7) * 8;   // staging coords: rows sr / sr+32, col blk scb

    for (int seg = 0; seg < 2; ++seg) {
        const int it = seg ? (15 - px) : px;
        const int i0 = it * 64;
        const int mb0 = 960 - i0;               // rel window base at jt=0

        __syncthreads();                        // prior segment's LDS reads done
        if (t < 64) ls[t] = 0.f;

        // q fragments live in registers for this i-tile
        bf8 aq[2];
#pragma unroll
        for (int ks = 0; ks < 2; ++ks)
            aq[ks] = *(const bf8*)(q + (qb + i0 + w * 16 + l15) * HDc + ks * 32 + quad * 8);

        // ================= pass A: row sums =================
        {   // prologue: stage jt=0 K + es halves 0,1 (rows mb0 .. mb0+127)
            const bf8 k0r = *(const bf8*)(k + (qb + sr) * HDc + scb);
            const bf8 k1r = *(const bf8*)(k + (qb + 32 + sr) * HDc + scb);
            *(bf8*)&kps[0][sr][scb] = k0r;
            *(bf8*)&kps[0][32 + sr][scb] = k1r;
#pragma unroll
            for (int s = 0; s < 4; ++s) {
                const int idx = s * 256 + t;
                const int r = idx >> 3, cb = (idx & 7) * 8;
                int row = mb0 + r; row = row > 1023 ? 1023 : row;  // OOB -> masked anyway
                *(bf8*)&es[r >> 6][r & 63][cb] = *(const bf8*)(rel + (size_t)row * HDc + cb);
            }
        }
        int cur = 0, h0 = 0, h1 = 1, h2 = 2;
        for (int jt = 0; jt <= it; ++jt) {
            const int j0 = jt * 64;
            __syncthreads();                    // buf[cur]/es writes visible; prev reads drained
            const bool pf = (jt < it);
            bf8 kn0 = {}, kn1 = {};
            if (pf) {                           // prefetch next K; stage es half for jt+1
                kn0 = *(const bf8*)(k + (qb + j0 + 64 + sr) * HDc + scb);
                kn1 = *(const bf8*)(k + (qb + j0 + 96 + sr) * HDc + scb);
                const int rb = mb0 + j0 + 128;
#pragma unroll
                for (int s = 0; s < 2; ++s) {
                    const int idx = s * 256 + t;
                    const int r = idx >> 3, cb = (idx & 7) * 8;
                    int row = rb + r; row = row > 1023 ? 1023 : row;
                    *(bf8*)&es[h2][r][cb] = *(const bf8*)(rel + (size_t)row * HDc + cb);
                }
            }

            f32x4 aS[4] = {}; f32x4 aR[5] = {};
#pragma unroll
            for (int ks = 0; ks < 2; ++ks) {
                const bf8 a = aq[ks];
#pragma unroll
                for (int nt = 0; nt < 4; ++nt) {
                    const bf8 b = *(const bf8*)&kps[cur][nt * 16 + l15][ks * 32 + quad * 8];
                    aS[nt] = __builtin_amdgcn_mfma_f32_16x16x32_bf16(a, b, aS[nt], 0, 0, 0);
                }
#pragma unroll
                for (int nt = 0; nt < 5; ++nt) {
                    const int rr = 3 - w + nt;   // rel row block within window (0..7)
                    const bf8 b = *(const bf8*)&es[(rr >= 4) ? h1 : h0]
                                                 [(rr & 3) * 16 + l15][ks * 32 + quad * 8];
                    aR[nt] = __builtin_amdgcn_mfma_f32_16x16x32_bf16(a, b, aR[nt], 0, 0, 0);
                }
            }
#pragma unroll
            for (int nt = 0; nt < 5; ++nt)
#pragma unroll
                for (int reg = 0; reg < 4; ++reg)
                    rs[w * 16 + quad * 4 + reg][nt * 16 + l15] = aR[nt][reg];

            float psum[4] = {0.f, 0.f, 0.f, 0.f};
#pragma unroll
            for (int nt = 0; nt < 4; ++nt) {
#pragma unroll
                for (int reg = 0; reg < 4; ++reg) {
                    const int Rl = w * 16 + quad * 4 + reg;
                    const int cp = 15 - quad * 4 - reg + nt * 16 + l15;  // rel window gather
                    const float sc = (aS[nt][reg] + rs[Rl][cp]) * 0.125f;
                    const bool valid = (j0 + nt * 16 + l15) <= (i0 + Rl);
                    psum[reg] += valid ? __expf(sc) : 0.f;
                }
            }
#pragma unroll
            for (int m = 1; m < 16; m <<= 1)
#pragma unroll
                for (int reg = 0; reg < 4; ++reg) psum[reg] += __shfl_xor(psum[reg], m, 64);
            if (l15 == 0) {
#pragma unroll
                for (int reg = 0; reg < 4; ++reg) ls[w * 16 + quad * 4 + reg] += psum[reg];
            }
            if (pf) {
                *(bf8*)&kps[cur ^ 1][sr][scb] = kn0;
                *(bf8*)&kps[cur ^ 1][32 + sr][scb] = kn1;
                cur ^= 1;
            }
            { const int tp = h0; h0 = h1; h1 = h2; h2 = tp; }   // advance rel ring
        }

        __syncthreads();                        // pass-A reads/accums done
        if (t < 64) ls[t] = 1.f / ls[t];

        f32x4 acc[4] = {};                      // PV accumulator (MFMA C layout)

        // ================= pass B: attn write + PV =================
        {   // prologue: stage jt=0 K + V + es halves 0,1
            const bf8 k0r = *(const bf8*)(k + (qb + sr) * HDc + scb);
            const bf8 k1r = *(const bf8*)(k + (qb + 32 + sr) * HDc + scb);
            S8 v0; v0.v = *(const bf8*)(v + (qb + sr) * HDc + scb);
            S8 v1; v1.v = *(const bf8*)(v + (qb + 32 + sr) * HDc + scb);
            *(bf8*)&kps[0][sr][scb] = k0r;
            *(bf8*)&kps[0][32 + sr][scb] = k1r;
            const int cp0 = (sr & 7) + 8 * (((sr >> 3) + (scb >> 3)) & 7);
            const int cp1 = (sr & 7) + 8 * ((4 + (sr >> 3) + (scb >> 3)) & 7);
#pragma unroll
            for (int u = 0; u < 8; ++u) vst[scb + u][cp0] = v0.s[u];
#pragma unroll
            for (int u = 0; u < 8; ++u) vst[scb + u][cp1] = v1.s[u];
#pragma unroll
            for (int s = 0; s < 4; ++s) {
                const int idx = s * 256 + t;
                const int r = idx >> 3, cb = (idx & 7) * 8;
                int row = mb0 + r; row = row > 1023 ? 1023 : row;
                *(bf8*)&es[r >> 6][r & 63][cb] = *(const bf8*)(rel + (size_t)row * HDc + cb);
            }
        }
        cur = 0; h0 = 0; h1 = 1; h2 = 2;
        for (int jt = 0; jt <= it; ++jt) {
            const int j0 = jt * 64;
            __syncthreads();                    // buf[cur]/vst/es ready; ls visible (jt=0)
            const bool pf = (jt < it);
            bf8 kn0 = {}, kn1 = {}, vn0 = {}, vn1 = {};
            if (pf) {
                kn0 = *(const bf8*)(k + (qb + j0 + 64 + sr) * HDc + scb);
                kn1 = *(const bf8*)(k + (qb + j0 + 96 + sr) * HDc + scb);
                vn0 = *(const bf8*)(v + (qb + j0 + 64 + sr) * HDc + scb);
                vn1 = *(const bf8*)(v + (qb + j0 + 96 + sr) * HDc + scb);
                const int rb = mb0 + j0 + 128;
#pragma unroll
                for (int s = 0; s < 2; ++s) {
                    const int idx = s * 256 + t;
                    const int r = idx >> 3, cb = (idx & 7) * 8;
                    int row = rb + r; row = row > 1023 ? 1023 : row;
                    *(bf8*)&es[h2][r][cb] = *(const bf8*)(rel + (size_t)row * HDc + cb);
                }
            }

            f32x4 aS[4] = {}; f32x4 aR[5] = {};
#pragma unroll
            for (int ks = 0; ks < 2; ++ks) {
                const bf8 a = aq[ks];
#pragma unroll
                for (int nt = 0; nt < 4; ++nt) {
                    const bf8 b = *(const bf8*)&kps[cur][nt * 16 + l15][ks * 32 + quad * 8];
                    aS[nt] = __builtin_amdgcn_mfma_f32_16x16x32_bf16(a, b, aS[nt], 0, 0, 0);
                }
#pragma unroll
                for (int nt = 0; nt < 5; ++nt) {
                    const int rr = 3 - w + nt;
                    const bf8 b = *(const bf8*)&es[(rr >= 4) ? h1 : h0]
                                                 [(rr & 3) * 16 + l15][ks * 32 + quad * 8];
                    aR[nt] = __builtin_amdgcn_mfma_f32_16x16x32_bf16(a, b, aR[nt], 0, 0, 0);
                }
            }
#pragma unroll
            for (int nt = 0; nt < 5; ++nt)
#pragma unroll
                for (int reg = 0; reg < 4; ++reg)
                    rs[w * 16 + quad * 4 + reg][nt * 16 + l15] = aR[nt][reg];

            // all gathers first (rel cols up to 78 must stay intact), then P writes
            float pvv[4][4];
#pragma unroll
            for (int nt = 0; nt < 4; ++nt) {
#pragma unroll
                for (int reg = 0; reg < 4; ++reg) {
                    const int Rl = w * 16 + quad * 4 + reg;
                    const int cp = 15 - quad * 4 - reg + nt * 16 + l15;
                    const float sc = (aS[nt][reg] + rs[Rl][cp]) * 0.125f;
                    const bool valid = (j0 + nt * 16 + l15) <= (i0 + Rl);
                    pvv[nt][reg] = valid ? __expf(sc) * ls[Rl] : 0.f;
                }
            }
            asm volatile("" ::: "memory");      // gathers (f32 reads) before P writes
#pragma unroll
            for (int nt = 0; nt < 4; ++nt) {
#pragma unroll
                for (int reg = 0; reg < 4; ++reg) {
                    const int Rl = w * 16 + quad * 4 + reg;
                    ((u16*)&rs[Rl][0])[nt * 16 + l15] = f2bf(pvv[nt][reg]);  // bf16 P, f32 cols 0..31
                    rs[Rl][32 + nt * 16 + l15] = pvv[nt][reg];               // f32 P, cols 32..95
                }
            }

            // PV via MFMA: acc[nt] += P(16x64) x V(64x16); p rows wave-private (in-order DS).
#pragma unroll
            for (int ks = 0; ks < 2; ++ks) {
                const bf8 pa = *(const bf8*)((const u16*)&rs[w * 16 + l15][0] + ks * 32 + quad * 8);
#pragma unroll
                for (int nt = 0; nt < 4; ++nt) {
                    const int d = nt * 16 + l15;
                    const bf8 vb = *(const bf8*)&vst[d][8 * (((ks * 4 + quad) + (d >> 3)) & 7)];
                    acc[nt] = __builtin_amdgcn_mfma_f32_16x16x32_bf16(pa, vb, acc[nt], 0, 0, 0);
                }
            }

            if (pf) {                           // next K into other dbuf half
                *(bf8*)&kps[cur ^ 1][sr][scb] = kn0;
                *(bf8*)&kps[cur ^ 1][32 + sr][scb] = kn1;
                cur ^= 1;
            }

            __syncthreads();                    // B2: all waves' f32 P visible; PV reads done
            // coalesced attn store: lanes 0-15 emit 256B/row, nontemporal (protect L2)
            const int trow = t >> 4, tcol = (t & 15) * 4;
#pragma unroll
            for (int s = 0; s < 4; ++s) {
                const f32x4 p4 = *(const f32x4*)&rs[trow + 16 * s][32 + tcol];
                __builtin_nontemporal_store(p4,
                    (f32x4*)(attn + ((size_t)bh * Lc + i0 + trow + 16 * s) * Lc + j0 + tcol));
            }
            if (pf) {                           // next V into (single) vst; visible at next TOP
                S8 a0; a0.v = vn0; S8 a1; a1.v = vn1;
                const int cp0 = (sr & 7) + 8 * (((sr >> 3) + (scb >> 3)) & 7);
                const int cp1 = (sr & 7) + 8 * ((4 + (sr >> 3) + (scb >> 3)) & 7);
#pragma unroll
                for (int u = 0; u < 8; ++u) vst[scb + u][cp0] = a0.s[u];
#pragma unroll
                for (int u = 0; u < 8; ++u) vst[scb + u][cp1] = a1.s[u];
            }
            { const int tp = h0; h0 = h1; h1 = h2; h2 = tp; }   // advance rel ring
            // next TOP barrier protects rs/vst/es from next-tile overwrites
        }

        // epilogue: out (already normalized), MFMA C layout
        const int bb = bh >> 3, hh = bh & 7;
#pragma unroll
        for (int nt = 0; nt < 4; ++nt)
#pragma unroll
            for (int reg = 0; reg < 4; ++reg)
                ows[((size_t)(bb * Lc + i0 + w * 16 + quad * 4 + reg)) * Dc + hh * HDc + nt * 16 + l15]
                    = f2bf(acc[nt][reg]);

        // zero-fill attn cols beyond the causal tiles (nontemporal)
        const int jend = (it + 1) * 64;
        if (jend + t * 4 < Lc) {
            const f32x4 z = {0.f, 0.f, 0.f, 0.f};
            for (int r = 0; r < 64; ++r)
                __builtin_nontemporal_store(z,
                    (f32x4*)(attn + ((size_t)bh * Lc + i0 + r) * Lc + jend + t * 4));
        }
    }
}

// ---------- launch ----------
extern "C" void kernel_launch(void* const* d_in, const int* in_sizes, int n_in,
                              void* d_out, int out_size, void* d_ws, size_t ws_size,
                              hipStream_t stream)
{
    const float* x_q = (const float*)d_in[0];
    const float* x_k = (const float*)d_in[1];
    const float* x_v = (const float*)d_in[2];
    // d_in[3] = mask — causal, folded analytically
    const float* Wq = (const float*)d_in[4];
    const float* bq = (const float*)d_in[5];
    const float* Wk = (const float*)d_in[6];
    const float* bk = (const float*)d_in[7];
    const float* Wv = (const float*)d_in[8];
    const float* bv = (const float*)d_in[9];
    const float* Wo = (const float*)d_in[10];
    const float* bo = (const float*)d_in[11];
    const float* rel = (const float*)d_in[12];

    float* out  = (float*)d_out;
    float* attn = out + (size_t)Bc * Lc * Dc;

    // ws carve (bf16)
    u16* relbf = (u16*)d_ws;                             // 1024*64
    u16* wqT = relbf + (size_t)1024 * 64;                // 512*512 each
    u16* wkT = wqT + (size_t)Dc * Dc;
    u16* wvT = wkT + (size_t)Dc * Dc;
    u16* woT = wvT + (size_t)Dc * Dc;
    u16* qbf = woT + (size_t)Dc * Dc;                    // head-split (B,H,L,HD)
    u16* kbf = qbf + (size_t)Bc * Lc * Dc;
    u16* vbf = kbf + (size_t)Bc * Lc * Dc;
    u16* owsbf = vbf + (size_t)Bc * Lc * Dc;             // (B,L,D) flat

    relcvt<<<64, 256, 0, stream>>>(rel, relbf);
    wtrans<<<dim3(8, 8, 4), 256, 0, stream>>>(Wq, Wk, Wv, Wo, wqT, wkT, wvT, woT);

    gemm_mfma<<<1024, 256, 0, stream>>>(x_q, wqT, bq, qbf, 1, 1);
    gemm_mfma<<<1024, 256, 0, stream>>>(x_k, wkT, bk, kbf, 1, 1);
    gemm_mfma<<<1024, 256, 0, stream>>>(x_v, wvT, bv, vbf, 1, 1);

    attn_mfma<<<dim3(64, 8), 256, 0, stream>>>(qbf, kbf, vbf, relbf, attn, owsbf);

    gemm_mfma<<<1024, 256, 0, stream>>>(owsbf, woT, bo, out, 0, 0);
}